// Round 4
// baseline (1155.247 us; speedup 1.0000x reference)
//
#include <hip/hip_runtime.h>
#include <hip/hip_bf16.h>

// ---------------------------------------------------------------------------
// EncoderBlock (differential attention + swiGLU FFN), MI355X / gfx950
// R3: attention t-split (NT=2). Fixed-max softmax partials are pure sums, so
//     each block handles half the keys; attn_reduce combines, normalizes,
//     applies lambda-diff + GroupNorm. 1024 blocks -> 4 waves/SIMD (was 2).
// ---------------------------------------------------------------------------

typedef __attribute__((ext_vector_type(8))) __bf16 bf16x8;
typedef __attribute__((ext_vector_type(4))) float f32x4;

#define GAS __attribute__((address_space(1)))
#define LAS __attribute__((address_space(3)))

__device__ __forceinline__ unsigned short f2bf(float f) {
  unsigned u = __float_as_uint(f);
  u += 0x7fffu + ((u >> 16) & 1u);   // RNE
  return (unsigned short)(u >> 16);
}
__device__ __forceinline__ float bf2f(unsigned short s) {
  return __uint_as_float(((unsigned)s) << 16);
}

// ---------------------------------------------------------------------------
// Transpose + convert: W[K][N] fp32 -> WT[N][K] bf16 * scale.
// ---------------------------------------------------------------------------
__global__ __launch_bounds__(256)
void transpose_cvt(const float* __restrict__ W, unsigned short* __restrict__ WT,
                   int K, int N, float scale) {
  __shared__ float tile[64][65];
  const int n0 = blockIdx.x * 64, k0 = blockIdx.y * 64;
  const int tr = threadIdx.x >> 4, tc = (threadIdx.x & 15) * 4;
#pragma unroll
  for (int i = 0; i < 4; ++i) {
    const float4 v = *(const float4*)&W[(size_t)(k0 + tr + i * 16) * N + n0 + tc];
    tile[tr + i * 16][tc + 0] = v.x;
    tile[tr + i * 16][tc + 1] = v.y;
    tile[tr + i * 16][tc + 2] = v.z;
    tile[tr + i * 16][tc + 3] = v.w;
  }
  __syncthreads();
#pragma unroll
  for (int i = 0; i < 4; ++i) {
    const int n = tr + i * 16;
    ushort4 o;
    o.x = f2bf(tile[tc + 0][n] * scale);
    o.y = f2bf(tile[tc + 1][n] * scale);
    o.z = f2bf(tile[tc + 2][n] * scale);
    o.w = f2bf(tile[tc + 3][n] * scale);
    *(ushort4*)&WT[(size_t)(n0 + n) * K + k0 + tc] = o;
  }
}

// ---------------------------------------------------------------------------
// V transpose (bf16): v[b,s,h*128+e] -> VT[(b*8+h)*128+e][S].
// ---------------------------------------------------------------------------
__global__ __launch_bounds__(256)
void v_transpose(const unsigned short* __restrict__ v, unsigned short* __restrict__ VT) {
  __shared__ unsigned short tile[64][65];
  const int s0 = blockIdx.x * 64, e0 = blockIdx.y * 64, bh = blockIdx.z;
  const int b = bh >> 3, h = bh & 7;
  const int tr = threadIdx.x >> 4, tc = (threadIdx.x & 15) * 4;
  const size_t inbase = (size_t)b * 2048 * 1024 + h * 128;
#pragma unroll
  for (int i = 0; i < 4; ++i) {
    const int r = tr + i * 16;
    const ushort4 val = *(const ushort4*)&v[inbase + (size_t)(s0 + r) * 1024 + e0 + tc];
    tile[r][tc + 0] = val.x;
    tile[r][tc + 1] = val.y;
    tile[r][tc + 2] = val.z;
    tile[r][tc + 3] = val.w;
  }
  __syncthreads();
#pragma unroll
  for (int i = 0; i < 4; ++i) {
    const int n = tr + i * 16;
    ushort4 oo;
    oo.x = tile[tc + 0][n];
    oo.y = tile[tc + 1][n];
    oo.z = tile[tc + 2][n];
    oo.w = tile[tc + 3][n];
    *(ushort4*)&VT[(size_t)(bh * 128 + e0 + n) * 2048 + s0 + tc] = oo;
  }
}

// ---------------------------------------------------------------------------
// lambda[h]
// ---------------------------------------------------------------------------
__global__ void lam_kernel(const float* __restrict__ lq1, const float* __restrict__ lk1,
                           const float* __restrict__ lq2, const float* __restrict__ lk2,
                           float* __restrict__ lam) {
  const int w = threadIdx.x >> 6, d = threadIdx.x & 63;
  float a = lq1[w * 64 + d] * lk1[w * 64 + d];
  float c = lq2[w * 64 + d] * lk2[w * 64 + d];
#pragma unroll
  for (int off = 32; off; off >>= 1) {
    a += __shfl_xor(a, off);
    c += __shfl_xor(c, off);
  }
  if (d == 0) lam[w] = __expf(a) - __expf(c) + 0.8f;
}

// ---------------------------------------------------------------------------
// LayerNorm over rows of 1024.
// ---------------------------------------------------------------------------
template <int WRITE_F32>
__global__ __launch_bounds__(256)
void ln_kernel(const float* __restrict__ x, const float* __restrict__ g,
               const float* __restrict__ bsh, unsigned short* __restrict__ obf,
               float* __restrict__ of32) {
  __shared__ float red[16];
  const int row = blockIdx.x, tid = threadIdx.x;
  const float4 v = *(const float4*)&x[(size_t)row * 1024 + tid * 4];
  float s = v.x + v.y + v.z + v.w;
  float q = v.x * v.x + v.y * v.y + v.z * v.z + v.w * v.w;
#pragma unroll
  for (int off = 32; off; off >>= 1) {
    s += __shfl_xor(s, off);
    q += __shfl_xor(q, off);
  }
  if ((tid & 63) == 0) {
    red[tid >> 6] = s;
    red[8 + (tid >> 6)] = q;
  }
  __syncthreads();
  s = red[0] + red[1] + red[2] + red[3];
  q = red[8] + red[9] + red[10] + red[11];
  const float mean = s * (1.f / 1024.f);
  const float var = q * (1.f / 1024.f) - mean * mean;
  const float rstd = rsqrtf(var + 1e-5f);
  const float4 gg = *(const float4*)&g[tid * 4];
  const float4 bb = *(const float4*)&bsh[tid * 4];
  float y0 = (v.x - mean) * rstd * gg.x + bb.x;
  float y1 = (v.y - mean) * rstd * gg.y + bb.y;
  float y2 = (v.z - mean) * rstd * gg.z + bb.z;
  float y3 = (v.w - mean) * rstd * gg.w + bb.w;
  const size_t base = (size_t)row * 1024 + tid * 4;
  ushort4 o;
  o.x = f2bf(y0); o.y = f2bf(y1); o.z = f2bf(y2); o.w = f2bf(y3);
  *(ushort4*)&obf[base] = o;
  if (WRITE_F32) {
    *(float4*)&of32[base] = make_float4(y0, y1, y2, y3);
  }
}

// ---------------------------------------------------------------------------
// GEMM: C[M][N] = A[M][K](bf16) @ BT[N][K](bf16)^T + bias*bscale.
// 128x128 tile, BK=32, 4 waves, global_load_lds(16B) staging.
// ---------------------------------------------------------------------------
template <int EPI>
__global__ __launch_bounds__(256)
void gemm_bf16(const unsigned short* __restrict__ A,
               const unsigned short* __restrict__ BT,
               const float* __restrict__ bias,
               const float* __restrict__ res,
               const unsigned short* __restrict__ gate_u,
               void* __restrict__ Cout, int M, int N, int K, float bscale) {
  __shared__ unsigned short ldsA[128 * 32];
  __shared__ unsigned short ldsB[128 * 32];
  const int tid = threadIdx.x;
  const int wv = tid >> 6, ln = tid & 63, lg = ln >> 4, lc = ln & 15;
  const int wm = wv >> 1, wn = wv & 1;
  const int m0 = blockIdx.y * 128, n0 = blockIdx.x * 128;
  const int rsub = ln >> 2, acol = (ln & 3) * 8;

  f32x4 acc[4][4];
#pragma unroll
  for (int i = 0; i < 4; ++i)
#pragma unroll
    for (int j = 0; j < 4; ++j) acc[i][j] = (f32x4)0.f;

  for (int k0 = 0; k0 < K; k0 += 32) {
#pragma unroll
    for (int j = 0; j < 2; ++j) {
      const int rowblk = wv * 32 + j * 16;
      const unsigned short* ga = A + (size_t)(m0 + rowblk + rsub) * K + (k0 + acol);
      __builtin_amdgcn_global_load_lds((GAS void*)ga, (LAS void*)&ldsA[rowblk * 32], 16, 0, 0);
      const unsigned short* gb = BT + (size_t)(n0 + rowblk + rsub) * K + (k0 + acol);
      __builtin_amdgcn_global_load_lds((GAS void*)gb, (LAS void*)&ldsB[rowblk * 32], 16, 0, 0);
    }
    __syncthreads();
    bf16x8 af[4], bf[4];
#pragma unroll
    for (int m = 0; m < 4; ++m)
      af[m] = *(const bf16x8*)&ldsA[(wm * 64 + m * 16 + lc) * 32 + lg * 8];
#pragma unroll
    for (int n = 0; n < 4; ++n)
      bf[n] = *(const bf16x8*)&ldsB[(wn * 64 + n * 16 + lc) * 32 + lg * 8];
#pragma unroll
    for (int m = 0; m < 4; ++m)
#pragma unroll
      for (int n = 0; n < 4; ++n)
        acc[m][n] = __builtin_amdgcn_mfma_f32_16x16x32_bf16(af[m], bf[n], acc[m][n], 0, 0, 0);
    __syncthreads();
  }

#pragma unroll
  for (int m = 0; m < 4; ++m) {
#pragma unroll
    for (int n = 0; n < 4; ++n) {
      const int c = n0 + wn * 64 + n * 16 + lc;
      const float bc = bias[c] * bscale;
#pragma unroll
      for (int j = 0; j < 4; ++j) {
        const int r = m0 + wm * 64 + m * 16 + lg * 4 + j;
        const size_t idx = (size_t)r * N + c;
        const float v = acc[m][n][j] + bc;
        if (EPI == 0) {
          ((unsigned short*)Cout)[idx] = f2bf(v);
        } else if (EPI == 1) {
          ((float*)Cout)[idx] = res[idx] + v;
        } else {
          const float uu = bf2f(gate_u[idx]);
          const float sw = v / (1.f + __expf(-v));   // silu
          ((unsigned short*)Cout)[idx] = f2bf(uu * sw);
        }
      }
    }
  }
}

// ---------------------------------------------------------------------------
// Differential attention partials, fixed-max softmax, t-split NT=2.
// grid(1024): bh=(id&7)+8*(id>>9) [XCD-clustered], qt=(id>>3)&31, tc=(id>>8)&1.
// Each block: 64 q-rows x 1024 keys. Writes Opart / lsumPart (pure sums).
// ---------------------------------------------------------------------------
__global__ __launch_bounds__(256, 4)
void attn_kernel(const unsigned short* __restrict__ q,
                 const unsigned short* __restrict__ k,
                 const unsigned short* __restrict__ VT,
                 float* __restrict__ Opart,
                 float* __restrict__ lsumPart) {
  constexpr int S = 2048;
  __shared__ unsigned short p_lds[4][2][2][512];   // [wave][buf][pair][16x32 swz]
  const int tid = threadIdx.x, w = tid >> 6, ln = tid & 63, lg = ln >> 4, lc = ln & 15;
  const int id = blockIdx.x;
  const int bh = (id & 7) + 8 * (id >> 9);
  const int qt = (id >> 3) & 31;
  const int tcn = (id >> 8) & 1;
  const size_t chan = (size_t)(bh >> 3) * S * 1024 + (bh & 7) * 128;
  const size_t vtbase = (size_t)bh * 128 * S;
  const int qrow = qt * 64 + w * 16 + lc;

  bf16x8 qf[2][2];
#pragma unroll
  for (int p = 0; p < 2; ++p)
#pragma unroll
    for (int ks = 0; ks < 2; ++ks)
      qf[p][ks] = *(const bf16x8*)&q[chan + (size_t)qrow * 1024 + p * 64 + ks * 32 + lg * 8];

  f32x4 O[2][8];
#pragma unroll
  for (int p = 0; p < 2; ++p)
#pragma unroll
    for (int ef = 0; ef < 8; ++ef) O[p][ef] = (f32x4)0.f;
  float lsum[2][4];
#pragma unroll
  for (int p = 0; p < 2; ++p)
#pragma unroll
    for (int j = 0; j < 4; ++j) lsum[p][j] = 0.f;

  const int prd = ((lc * 64 + lg * 16) ^ ((lc & 7) << 4)) >> 1;   // PV A-frag read

  auto tile = [&](int t0, int buf) {
    bf16x8 vf[8];
#pragma unroll
    for (int ef = 0; ef < 8; ++ef)
      vf[ef] = *(const bf16x8*)&VT[vtbase + (size_t)(ef * 16 + lc) * S + t0 + lg * 8];

#pragma unroll
    for (int p = 0; p < 2; ++p) {
      bf16x8 kf[2][2];
#pragma unroll
      for (int tf = 0; tf < 2; ++tf)
#pragma unroll
        for (int ks = 0; ks < 2; ++ks)
          kf[tf][ks] = *(const bf16x8*)&k[chan + (size_t)(t0 + tf * 16 + lc) * 1024 +
                                          p * 64 + ks * 32 + lg * 8];
      f32x4 sfr[2];
      __builtin_amdgcn_s_setprio(1);
#pragma unroll
      for (int tf = 0; tf < 2; ++tf) {
        f32x4 acc = (f32x4)0.f;
#pragma unroll
        for (int ks = 0; ks < 2; ++ks)
          acc = __builtin_amdgcn_mfma_f32_16x16x32_bf16(qf[p][ks], kf[tf][ks], acc, 0, 0, 0);
        sfr[tf] = acc;
      }
      __builtin_amdgcn_s_setprio(0);

#pragma unroll
      for (int tf = 0; tf < 2; ++tf)
#pragma unroll
        for (int j = 0; j < 4; ++j) {
          const float e = __expf(sfr[tf][j]);
          lsum[p][j] += e;
          const int qq = lg * 4 + j;
          const int wi = ((qq * 64 + (tf * 16 + lc) * 2) ^ ((qq & 7) << 4)) >> 1;
          p_lds[w][buf][p][wi] = f2bf(e);
        }

      const bf16x8 pa = *(const bf16x8*)&p_lds[w][buf][p][prd];
      __builtin_amdgcn_s_setprio(1);
#pragma unroll
      for (int ef = 0; ef < 8; ++ef)
        O[p][ef] = __builtin_amdgcn_mfma_f32_16x16x32_bf16(pa, vf[ef], O[p][ef], 0, 0, 0);
      __builtin_amdgcn_s_setprio(0);
    }
  };

  const int tbeg = tcn * (S / 2);
  for (int t0 = tbeg; t0 < tbeg + S / 2; t0 += 64) {
    tile(t0, 0);
    tile(t0 + 32, 1);
  }

  // write partials
  const size_t rowbase = ((size_t)tcn * 16 + bh) * S;
#pragma unroll
  for (int p = 0; p < 2; ++p)
#pragma unroll
    for (int j = 0; j < 4; ++j) {
      float s = lsum[p][j];
      s += __shfl_xor(s, 1);
      s += __shfl_xor(s, 2);
      s += __shfl_xor(s, 4);
      s += __shfl_xor(s, 8);
      const int row = qt * 64 + w * 16 + lg * 4 + j;
      if (lc == 0)
        lsumPart[(rowbase + row) * 2 + p] = s;
#pragma unroll
      for (int ef = 0; ef < 8; ++ef)
        Opart[(rowbase + row) * 256 + p * 128 + ef * 16 + lc] = O[p][ef][j];
    }
}

// ---------------------------------------------------------------------------
// Combine t-chunk partials: normalize, lambda-diff, headwise GroupNorm, *0.2.
// One wave per (bh, s) row; 256-thr blocks; grid = 32768/4.
// ---------------------------------------------------------------------------
__global__ __launch_bounds__(256)
void attn_reduce(const float* __restrict__ Opart, const float* __restrict__ lsumPart,
                 const float* __restrict__ lam,
                 const float* __restrict__ gn_w, const float* __restrict__ gn_b,
                 unsigned short* __restrict__ o) {
  constexpr int S = 2048;
  const int gw = (blockIdx.x * 256 + threadIdx.x) >> 6;
  const int ln = threadIdx.x & 63;
  const int bh = gw >> 11, s = gw & 2047;
  const int b = bh >> 3, h = bh & 7;
  const size_t r0 = ((size_t)bh * S + s) * 256;
  const size_t r1 = (((size_t)16 + bh) * S + s) * 256;
  const int e = ln * 2;
  const float2 o1a = *(const float2*)&Opart[r0 + e];
  const float2 o1b = *(const float2*)&Opart[r1 + e];
  const float2 o2a = *(const float2*)&Opart[r0 + 128 + e];
  const float2 o2b = *(const float2*)&Opart[r1 + 128 + e];
  const size_t l0 = ((size_t)bh * S + s) * 2;
  const size_t l1 = (((size_t)16 + bh) * S + s) * 2;
  const float inv1 = 1.f / (lsumPart[l0] + lsumPart[l1]);
  const float inv2 = lam[h] / (lsumPart[l0 + 1] + lsumPart[l1 + 1]);
  float d0 = (o1a.x + o1b.x) * inv1 - (o2a.x + o2b.x) * inv2;
  float d1 = (o1a.y + o1b.y) * inv1 - (o2a.y + o2b.y) * inv2;
  float sum = d0 + d1, sq = d0 * d0 + d1 * d1;
#pragma unroll
  for (int off = 32; off; off >>= 1) {
    sum += __shfl_xor(sum, off);
    sq += __shfl_xor(sq, off);
  }
  const float mean = sum * (1.f / 128.f);
  const float var = sq * (1.f / 128.f) - mean * mean;
  const float rstd = rsqrtf(var + 1e-5f);
  const float v0 = ((d0 - mean) * rstd * gn_w[h * 128 + e] + gn_b[h * 128 + e]) * 0.2f;
  const float v1 = ((d1 - mean) * rstd * gn_w[h * 128 + e + 1] + gn_b[h * 128 + e + 1]) * 0.2f;
  ushort2 ov;
  ov.x = f2bf(v0);
  ov.y = f2bf(v1);
  *(ushort2*)&o[(size_t)b * S * 1024 + (size_t)s * 1024 + h * 128 + e] = ov;
}

// ---------------------------------------------------------------------------
extern "C" void kernel_launch(void* const* d_in, const int* in_sizes, int n_in,
                              void* d_out, int out_size, void* d_ws, size_t ws_size,
                              hipStream_t stream) {
  (void)in_sizes; (void)n_in; (void)out_size; (void)ws_size;
  const float* x    = (const float*)d_in[0];
  const float* ln1g = (const float*)d_in[1];
  const float* ln1b = (const float*)d_in[2];
  const float* ln2g = (const float*)d_in[3];
  const float* ln2b = (const float*)d_in[4];
  const float* Wq   = (const float*)d_in[5];
  const float* bq   = (const float*)d_in[6];
  const float* Wk   = (const float*)d_in[7];
  const float* bk   = (const float*)d_in[8];
  const float* Wv   = (const float*)d_in[9];
  const float* bv   = (const float*)d_in[10];
  const float* Wo   = (const float*)d_in[11];
  const float* bo   = (const float*)d_in[12];
  const float* lq1  = (const float*)d_in[13];
  const float* lk1  = (const float*)d_in[14];
  const float* lq2  = (const float*)d_in[15];
  const float* lk2  = (const float*)d_in[16];
  const float* gnw  = (const float*)d_in[17];
  const float* gnb  = (const float*)d_in[18];
  const float* W1   = (const float*)d_in[19];
  const float* b1   = (const float*)d_in[20];
  const float* Wg   = (const float*)d_in[21];
  const float* bg   = (const float*)d_in[22];
  const float* W2   = (const float*)d_in[23];
  const float* b2   = (const float*)d_in[24];

  const int B = 2, S = 2048, D = 1024, F = 4096;
  const int M = B * S;  // 4096
  const float qscale = 0.125f;

  char* ws = (char*)d_ws;
  size_t off = 0;
  auto alloc = [&](size_t bytes) {
    char* p = ws + off;
    off += (bytes + 255) & ~(size_t)255;
    return p;
  };
  unsigned short* WqT = (unsigned short*)alloc((size_t)D * D * 2);
  unsigned short* WkT = (unsigned short*)alloc((size_t)D * D * 2);
  unsigned short* WvT = (unsigned short*)alloc((size_t)D * D * 2);
  unsigned short* WoT = (unsigned short*)alloc((size_t)D * D * 2);
  unsigned short* W1T = (unsigned short*)alloc((size_t)F * D * 2);
  unsigned short* WgT = (unsigned short*)alloc((size_t)F * F * 2);
  unsigned short* W2T = (unsigned short*)alloc((size_t)D * F * 2);
  float*          lamw= (float*)alloc(256);
  unsigned short* h_bf= (unsigned short*)alloc((size_t)M * D * 2);
  unsigned short* q_bf= (unsigned short*)alloc((size_t)M * D * 2);
  unsigned short* k_bf= (unsigned short*)alloc((size_t)M * D * 2);
  unsigned short* v_bf= (unsigned short*)alloc((size_t)M * D * 2);
  unsigned short* o_bf= (unsigned short*)alloc((size_t)M * D * 2);
  float*          x1  = (float*)alloc((size_t)M * D * 4);
  float*          x2  = (float*)alloc((size_t)M * D * 4);
  unsigned short* x2b = (unsigned short*)alloc((size_t)M * D * 2);
  unsigned short* u_bf= (unsigned short*)alloc((size_t)M * F * 2);
  unsigned short* w_bf= h_bf;   // gated act reuses h span (dead after q/k/v GEMMs)

  // Attention scratch overlays (all consumed before their hosts are written):
  float* Opart = (float*)x1;                          // 64MB: x1+x2+x2b+u_bf[0:24MB)
  float* lsumP = (float*)h_bf;                        // 1MB in dead h span? no - h live!
  // h_bf holds LN1 output, still needed... use o_bf tail instead? o_bf written by
  // reduce itself. Use q_bf? q live during attn. SAFE spot: x2 span is inside
  // Opart. Place lsumP in the last MB of o_bf? o_bf written only by attn_reduce
  // (after lsumP reads) - but reduce writes o_bf while reading lsumP. o_bf is
  // 8MB, lsumP 1MB; reduce reads lsumP[row] then writes o_bf[row] - overlap
  // hazard. Instead: extend allocation - put lsumP AFTER u_bf (fresh 1MB).
  float* lsumP2 = (float*)alloc((size_t)2 * 16 * S * 2 * 4);   // 1MB fresh
  lsumP = lsumP2;
  unsigned short* VT = u_bf + (size_t)12 * 1024 * 1024;  // last 8MB of u_bf span

  // --- weight prep ---
  transpose_cvt<<<dim3(D / 64, D / 64), 256, 0, stream>>>(Wq, WqT, D, D, qscale);
  transpose_cvt<<<dim3(D / 64, D / 64), 256, 0, stream>>>(Wk, WkT, D, D, 1.0f);
  transpose_cvt<<<dim3(D / 64, D / 64), 256, 0, stream>>>(Wv, WvT, D, D, 1.0f);
  transpose_cvt<<<dim3(D / 64, D / 64), 256, 0, stream>>>(Wo, WoT, D, D, 1.0f);
  transpose_cvt<<<dim3(F / 64, D / 64), 256, 0, stream>>>(W1, W1T, D, F, 1.0f);
  transpose_cvt<<<dim3(F / 64, F / 64), 256, 0, stream>>>(Wg, WgT, F, F, 1.0f);
  transpose_cvt<<<dim3(D / 64, F / 64), 256, 0, stream>>>(W2, W2T, F, D, 1.0f);
  lam_kernel<<<1, 512, 0, stream>>>(lq1, lk1, lq2, lk2, lamw);

  // --- attention sublayer ---
  ln_kernel<0><<<M, 256, 0, stream>>>(x, ln1g, ln1b, h_bf, nullptr);
  gemm_bf16<0><<<dim3(D / 128, M / 128), 256, 0, stream>>>(h_bf, WqT, bq, nullptr, nullptr, q_bf, M, D, D, qscale);
  gemm_bf16<0><<<dim3(D / 128, M / 128), 256, 0, stream>>>(h_bf, WkT, bk, nullptr, nullptr, k_bf, M, D, D, 1.0f);
  gemm_bf16<0><<<dim3(D / 128, M / 128), 256, 0, stream>>>(h_bf, WvT, bv, nullptr, nullptr, v_bf, M, D, D, 1.0f);
  v_transpose<<<dim3(S / 64, 2, 16), 256, 0, stream>>>(v_bf, VT);
  attn_kernel<<<dim3(1024), 256, 0, stream>>>(q_bf, k_bf, VT, Opart, lsumP);
  attn_reduce<<<dim3(8192), 256, 0, stream>>>(Opart, lsumP, lamw, gnw, gnb, o_bf);
  gemm_bf16<1><<<dim3(D / 128, M / 128), 256, 0, stream>>>(o_bf, WoT, bo, x, nullptr, x1, M, D, D, 1.0f);

  // --- FFN sublayer ---
  ln_kernel<1><<<M, 256, 0, stream>>>(x1, ln2g, ln2b, x2b, x2);
  gemm_bf16<0><<<dim3(F / 128, M / 128), 256, 0, stream>>>(x2b, W1T, b1, nullptr, nullptr, u_bf, M, F, D, 1.0f);
  gemm_bf16<2><<<dim3(F / 128, M / 128), 256, 0, stream>>>(u_bf, WgT, bg, nullptr, u_bf, w_bf, M, F, F, 1.0f);
  gemm_bf16<1><<<dim3(D / 128, M / 128), 256, 0, stream>>>(w_bf, W2T, b2, x2, nullptr, (float*)d_out, M, D, F, 1.0f);
}

// Round 5
// 765.474 us; speedup vs baseline: 1.5092x; 1.5092x over previous
//
#include <hip/hip_runtime.h>
#include <hip/hip_bf16.h>

// ---------------------------------------------------------------------------
// EncoderBlock (differential attention + swiGLU FFN), MI355X / gfx950
// R4: fix R3's VGPR-spill catastrophe — __launch_bounds__(256,4) forced 64
//     VGPRs and spilled the O accumulators (1.6GB scratch writes/dispatch).
//     Plain __launch_bounds__(256): ~104 VGPR -> 4 waves/SIMD naturally.
//     t-split NT=2 + fixed-max softmax retained.
// ---------------------------------------------------------------------------

typedef __attribute__((ext_vector_type(8))) __bf16 bf16x8;
typedef __attribute__((ext_vector_type(4))) float f32x4;

#define GAS __attribute__((address_space(1)))
#define LAS __attribute__((address_space(3)))

__device__ __forceinline__ unsigned short f2bf(float f) {
  unsigned u = __float_as_uint(f);
  u += 0x7fffu + ((u >> 16) & 1u);   // RNE
  return (unsigned short)(u >> 16);
}
__device__ __forceinline__ float bf2f(unsigned short s) {
  return __uint_as_float(((unsigned)s) << 16);
}

// ---------------------------------------------------------------------------
// Transpose + convert: W[K][N] fp32 -> WT[N][K] bf16 * scale.
// ---------------------------------------------------------------------------
__global__ __launch_bounds__(256)
void transpose_cvt(const float* __restrict__ W, unsigned short* __restrict__ WT,
                   int K, int N, float scale) {
  __shared__ float tile[64][65];
  const int n0 = blockIdx.x * 64, k0 = blockIdx.y * 64;
  const int tr = threadIdx.x >> 4, tc = (threadIdx.x & 15) * 4;
#pragma unroll
  for (int i = 0; i < 4; ++i) {
    const float4 v = *(const float4*)&W[(size_t)(k0 + tr + i * 16) * N + n0 + tc];
    tile[tr + i * 16][tc + 0] = v.x;
    tile[tr + i * 16][tc + 1] = v.y;
    tile[tr + i * 16][tc + 2] = v.z;
    tile[tr + i * 16][tc + 3] = v.w;
  }
  __syncthreads();
#pragma unroll
  for (int i = 0; i < 4; ++i) {
    const int n = tr + i * 16;
    ushort4 o;
    o.x = f2bf(tile[tc + 0][n] * scale);
    o.y = f2bf(tile[tc + 1][n] * scale);
    o.z = f2bf(tile[tc + 2][n] * scale);
    o.w = f2bf(tile[tc + 3][n] * scale);
    *(ushort4*)&WT[(size_t)(n0 + n) * K + k0 + tc] = o;
  }
}

// ---------------------------------------------------------------------------
// V transpose (bf16): v[b,s,h*128+e] -> VT[(b*8+h)*128+e][S].
// ---------------------------------------------------------------------------
__global__ __launch_bounds__(256)
void v_transpose(const unsigned short* __restrict__ v, unsigned short* __restrict__ VT) {
  __shared__ unsigned short tile[64][65];
  const int s0 = blockIdx.x * 64, e0 = blockIdx.y * 64, bh = blockIdx.z;
  const int b = bh >> 3, h = bh & 7;
  const int tr = threadIdx.x >> 4, tc = (threadIdx.x & 15) * 4;
  const size_t inbase = (size_t)b * 2048 * 1024 + h * 128;
#pragma unroll
  for (int i = 0; i < 4; ++i) {
    const int r = tr + i * 16;
    const ushort4 val = *(const ushort4*)&v[inbase + (size_t)(s0 + r) * 1024 + e0 + tc];
    tile[r][tc + 0] = val.x;
    tile[r][tc + 1] = val.y;
    tile[r][tc + 2] = val.z;
    tile[r][tc + 3] = val.w;
  }
  __syncthreads();
#pragma unroll
  for (int i = 0; i < 4; ++i) {
    const int n = tr + i * 16;
    ushort4 oo;
    oo.x = tile[tc + 0][n];
    oo.y = tile[tc + 1][n];
    oo.z = tile[tc + 2][n];
    oo.w = tile[tc + 3][n];
    *(ushort4*)&VT[(size_t)(bh * 128 + e0 + n) * 2048 + s0 + tc] = oo;
  }
}

// ---------------------------------------------------------------------------
// lambda[h]
// ---------------------------------------------------------------------------
__global__ void lam_kernel(const float* __restrict__ lq1, const float* __restrict__ lk1,
                           const float* __restrict__ lq2, const float* __restrict__ lk2,
                           float* __restrict__ lam) {
  const int w = threadIdx.x >> 6, d = threadIdx.x & 63;
  float a = lq1[w * 64 + d] * lk1[w * 64 + d];
  float c = lq2[w * 64 + d] * lk2[w * 64 + d];
#pragma unroll
  for (int off = 32; off; off >>= 1) {
    a += __shfl_xor(a, off);
    c += __shfl_xor(c, off);
  }
  if (d == 0) lam[w] = __expf(a) - __expf(c) + 0.8f;
}

// ---------------------------------------------------------------------------
// LayerNorm over rows of 1024.
// ---------------------------------------------------------------------------
template <int WRITE_F32>
__global__ __launch_bounds__(256)
void ln_kernel(const float* __restrict__ x, const float* __restrict__ g,
               const float* __restrict__ bsh, unsigned short* __restrict__ obf,
               float* __restrict__ of32) {
  __shared__ float red[16];
  const int row = blockIdx.x, tid = threadIdx.x;
  const float4 v = *(const float4*)&x[(size_t)row * 1024 + tid * 4];
  float s = v.x + v.y + v.z + v.w;
  float q = v.x * v.x + v.y * v.y + v.z * v.z + v.w * v.w;
#pragma unroll
  for (int off = 32; off; off >>= 1) {
    s += __shfl_xor(s, off);
    q += __shfl_xor(q, off);
  }
  if ((tid & 63) == 0) {
    red[tid >> 6] = s;
    red[8 + (tid >> 6)] = q;
  }
  __syncthreads();
  s = red[0] + red[1] + red[2] + red[3];
  q = red[8] + red[9] + red[10] + red[11];
  const float mean = s * (1.f / 1024.f);
  const float var = q * (1.f / 1024.f) - mean * mean;
  const float rstd = rsqrtf(var + 1e-5f);
  const float4 gg = *(const float4*)&g[tid * 4];
  const float4 bb = *(const float4*)&bsh[tid * 4];
  float y0 = (v.x - mean) * rstd * gg.x + bb.x;
  float y1 = (v.y - mean) * rstd * gg.y + bb.y;
  float y2 = (v.z - mean) * rstd * gg.z + bb.z;
  float y3 = (v.w - mean) * rstd * gg.w + bb.w;
  const size_t base = (size_t)row * 1024 + tid * 4;
  ushort4 o;
  o.x = f2bf(y0); o.y = f2bf(y1); o.z = f2bf(y2); o.w = f2bf(y3);
  *(ushort4*)&obf[base] = o;
  if (WRITE_F32) {
    *(float4*)&of32[base] = make_float4(y0, y1, y2, y3);
  }
}

// ---------------------------------------------------------------------------
// GEMM: C[M][N] = A[M][K](bf16) @ BT[N][K](bf16)^T + bias*bscale.
// 128x128 tile, BK=32, 4 waves, global_load_lds(16B) staging.
// ---------------------------------------------------------------------------
template <int EPI>
__global__ __launch_bounds__(256)
void gemm_bf16(const unsigned short* __restrict__ A,
               const unsigned short* __restrict__ BT,
               const float* __restrict__ bias,
               const float* __restrict__ res,
               const unsigned short* __restrict__ gate_u,
               void* __restrict__ Cout, int M, int N, int K, float bscale) {
  __shared__ unsigned short ldsA[128 * 32];
  __shared__ unsigned short ldsB[128 * 32];
  const int tid = threadIdx.x;
  const int wv = tid >> 6, ln = tid & 63, lg = ln >> 4, lc = ln & 15;
  const int wm = wv >> 1, wn = wv & 1;
  const int m0 = blockIdx.y * 128, n0 = blockIdx.x * 128;
  const int rsub = ln >> 2, acol = (ln & 3) * 8;

  f32x4 acc[4][4];
#pragma unroll
  for (int i = 0; i < 4; ++i)
#pragma unroll
    for (int j = 0; j < 4; ++j) acc[i][j] = (f32x4)0.f;

  for (int k0 = 0; k0 < K; k0 += 32) {
#pragma unroll
    for (int j = 0; j < 2; ++j) {
      const int rowblk = wv * 32 + j * 16;
      const unsigned short* ga = A + (size_t)(m0 + rowblk + rsub) * K + (k0 + acol);
      __builtin_amdgcn_global_load_lds((GAS void*)ga, (LAS void*)&ldsA[rowblk * 32], 16, 0, 0);
      const unsigned short* gb = BT + (size_t)(n0 + rowblk + rsub) * K + (k0 + acol);
      __builtin_amdgcn_global_load_lds((GAS void*)gb, (LAS void*)&ldsB[rowblk * 32], 16, 0, 0);
    }
    __syncthreads();
    bf16x8 af[4], bf[4];
#pragma unroll
    for (int m = 0; m < 4; ++m)
      af[m] = *(const bf16x8*)&ldsA[(wm * 64 + m * 16 + lc) * 32 + lg * 8];
#pragma unroll
    for (int n = 0; n < 4; ++n)
      bf[n] = *(const bf16x8*)&ldsB[(wn * 64 + n * 16 + lc) * 32 + lg * 8];
#pragma unroll
    for (int m = 0; m < 4; ++m)
#pragma unroll
      for (int n = 0; n < 4; ++n)
        acc[m][n] = __builtin_amdgcn_mfma_f32_16x16x32_bf16(af[m], bf[n], acc[m][n], 0, 0, 0);
    __syncthreads();
  }

#pragma unroll
  for (int m = 0; m < 4; ++m) {
#pragma unroll
    for (int n = 0; n < 4; ++n) {
      const int c = n0 + wn * 64 + n * 16 + lc;
      const float bc = bias[c] * bscale;
#pragma unroll
      for (int j = 0; j < 4; ++j) {
        const int r = m0 + wm * 64 + m * 16 + lg * 4 + j;
        const size_t idx = (size_t)r * N + c;
        const float v = acc[m][n][j] + bc;
        if (EPI == 0) {
          ((unsigned short*)Cout)[idx] = f2bf(v);
        } else if (EPI == 1) {
          ((float*)Cout)[idx] = res[idx] + v;
        } else {
          const float uu = bf2f(gate_u[idx]);
          const float sw = v / (1.f + __expf(-v));   // silu
          ((unsigned short*)Cout)[idx] = f2bf(uu * sw);
        }
      }
    }
  }
}

// ---------------------------------------------------------------------------
// Differential attention partials, fixed-max softmax, t-split NT=2.
// grid(1024): bh=(id&7)+8*(id>>9) [XCD-clustered], qt=(id>>3)&31, tc=(id>>8)&1.
// Each block: 64 q-rows x 1024 keys. Writes Opart / lsumPart (pure sums).
// NOTE: no min-waves clamp — needs ~104 VGPR; (256,4) forced 64 and spilled.
// ---------------------------------------------------------------------------
__global__ __launch_bounds__(256)
void attn_kernel(const unsigned short* __restrict__ q,
                 const unsigned short* __restrict__ k,
                 const unsigned short* __restrict__ VT,
                 float* __restrict__ Opart,
                 float* __restrict__ lsumPart) {
  constexpr int S = 2048;
  __shared__ unsigned short p_lds[4][2][2][512];   // [wave][buf][pair][16x32 swz]
  const int tid = threadIdx.x, w = tid >> 6, ln = tid & 63, lg = ln >> 4, lc = ln & 15;
  const int id = blockIdx.x;
  const int bh = (id & 7) + 8 * (id >> 9);
  const int qt = (id >> 3) & 31;
  const int tcn = (id >> 8) & 1;
  const size_t chan = (size_t)(bh >> 3) * S * 1024 + (bh & 7) * 128;
  const size_t vtbase = (size_t)bh * 128 * S;
  const int qrow = qt * 64 + w * 16 + lc;

  bf16x8 qf[2][2];
#pragma unroll
  for (int p = 0; p < 2; ++p)
#pragma unroll
    for (int ks = 0; ks < 2; ++ks)
      qf[p][ks] = *(const bf16x8*)&q[chan + (size_t)qrow * 1024 + p * 64 + ks * 32 + lg * 8];

  f32x4 O[2][8];
#pragma unroll
  for (int p = 0; p < 2; ++p)
#pragma unroll
    for (int ef = 0; ef < 8; ++ef) O[p][ef] = (f32x4)0.f;
  float lsum[2][4];
#pragma unroll
  for (int p = 0; p < 2; ++p)
#pragma unroll
    for (int j = 0; j < 4; ++j) lsum[p][j] = 0.f;

  const int prd = ((lc * 64 + lg * 16) ^ ((lc & 7) << 4)) >> 1;   // PV A-frag read

  auto tile = [&](int t0, int buf) {
    bf16x8 vf[8];
#pragma unroll
    for (int ef = 0; ef < 8; ++ef)
      vf[ef] = *(const bf16x8*)&VT[vtbase + (size_t)(ef * 16 + lc) * S + t0 + lg * 8];

#pragma unroll
    for (int p = 0; p < 2; ++p) {
      bf16x8 kf[2][2];
#pragma unroll
      for (int tf = 0; tf < 2; ++tf)
#pragma unroll
        for (int ks = 0; ks < 2; ++ks)
          kf[tf][ks] = *(const bf16x8*)&k[chan + (size_t)(t0 + tf * 16 + lc) * 1024 +
                                          p * 64 + ks * 32 + lg * 8];
      f32x4 sfr[2];
      __builtin_amdgcn_s_setprio(1);
#pragma unroll
      for (int tf = 0; tf < 2; ++tf) {
        f32x4 acc = (f32x4)0.f;
#pragma unroll
        for (int ks = 0; ks < 2; ++ks)
          acc = __builtin_amdgcn_mfma_f32_16x16x32_bf16(qf[p][ks], kf[tf][ks], acc, 0, 0, 0);
        sfr[tf] = acc;
      }
      __builtin_amdgcn_s_setprio(0);

#pragma unroll
      for (int tf = 0; tf < 2; ++tf)
#pragma unroll
        for (int j = 0; j < 4; ++j) {
          const float e = __expf(sfr[tf][j]);
          lsum[p][j] += e;
          const int qq = lg * 4 + j;
          const int wi = ((qq * 64 + (tf * 16 + lc) * 2) ^ ((qq & 7) << 4)) >> 1;
          p_lds[w][buf][p][wi] = f2bf(e);
        }

      const bf16x8 pa = *(const bf16x8*)&p_lds[w][buf][p][prd];
      __builtin_amdgcn_s_setprio(1);
#pragma unroll
      for (int ef = 0; ef < 8; ++ef)
        O[p][ef] = __builtin_amdgcn_mfma_f32_16x16x32_bf16(pa, vf[ef], O[p][ef], 0, 0, 0);
      __builtin_amdgcn_s_setprio(0);
    }
  };

  const int tbeg = tcn * (S / 2);
  for (int t0 = tbeg; t0 < tbeg + S / 2; t0 += 64) {
    tile(t0, 0);
    tile(t0 + 32, 1);
  }

  // write partials
  const size_t rowbase = ((size_t)tcn * 16 + bh) * S;
#pragma unroll
  for (int p = 0; p < 2; ++p)
#pragma unroll
    for (int j = 0; j < 4; ++j) {
      float s = lsum[p][j];
      s += __shfl_xor(s, 1);
      s += __shfl_xor(s, 2);
      s += __shfl_xor(s, 4);
      s += __shfl_xor(s, 8);
      const int row = qt * 64 + w * 16 + lg * 4 + j;
      if (lc == 0)
        lsumPart[(rowbase + row) * 2 + p] = s;
#pragma unroll
      for (int ef = 0; ef < 8; ++ef)
        Opart[(rowbase + row) * 256 + p * 128 + ef * 16 + lc] = O[p][ef][j];
    }
}

// ---------------------------------------------------------------------------
// Combine t-chunk partials: normalize, lambda-diff, headwise GroupNorm, *0.2.
// ---------------------------------------------------------------------------
__global__ __launch_bounds__(256)
void attn_reduce(const float* __restrict__ Opart, const float* __restrict__ lsumPart,
                 const float* __restrict__ lam,
                 const float* __restrict__ gn_w, const float* __restrict__ gn_b,
                 unsigned short* __restrict__ o) {
  constexpr int S = 2048;
  const int gw = (blockIdx.x * 256 + threadIdx.x) >> 6;
  const int ln = threadIdx.x & 63;
  const int bh = gw >> 11, s = gw & 2047;
  const int b = bh >> 3, h = bh & 7;
  const size_t r0 = ((size_t)bh * S + s) * 256;
  const size_t r1 = (((size_t)16 + bh) * S + s) * 256;
  const int e = ln * 2;
  const float2 o1a = *(const float2*)&Opart[r0 + e];
  const float2 o1b = *(const float2*)&Opart[r1 + e];
  const float2 o2a = *(const float2*)&Opart[r0 + 128 + e];
  const float2 o2b = *(const float2*)&Opart[r1 + 128 + e];
  const size_t l0 = ((size_t)bh * S + s) * 2;
  const size_t l1 = (((size_t)16 + bh) * S + s) * 2;
  const float inv1 = 1.f / (lsumPart[l0] + lsumPart[l1]);
  const float inv2 = lam[h] / (lsumPart[l0 + 1] + lsumPart[l1 + 1]);
  float d0 = (o1a.x + o1b.x) * inv1 - (o2a.x + o2b.x) * inv2;
  float d1 = (o1a.y + o1b.y) * inv1 - (o2a.y + o2b.y) * inv2;
  float sum = d0 + d1, sq = d0 * d0 + d1 * d1;
#pragma unroll
  for (int off = 32; off; off >>= 1) {
    sum += __shfl_xor(sum, off);
    sq += __shfl_xor(sq, off);
  }
  const float mean = sum * (1.f / 128.f);
  const float var = sq * (1.f / 128.f) - mean * mean;
  const float rstd = rsqrtf(var + 1e-5f);
  const float v0 = ((d0 - mean) * rstd * gn_w[h * 128 + e] + gn_b[h * 128 + e]) * 0.2f;
  const float v1 = ((d1 - mean) * rstd * gn_w[h * 128 + e + 1] + gn_b[h * 128 + e + 1]) * 0.2f;
  ushort2 ov;
  ov.x = f2bf(v0);
  ov.y = f2bf(v1);
  *(ushort2*)&o[(size_t)b * S * 1024 + (size_t)s * 1024 + h * 128 + e] = ov;
}

// ---------------------------------------------------------------------------
extern "C" void kernel_launch(void* const* d_in, const int* in_sizes, int n_in,
                              void* d_out, int out_size, void* d_ws, size_t ws_size,
                              hipStream_t stream) {
  (void)in_sizes; (void)n_in; (void)out_size; (void)ws_size;
  const float* x    = (const float*)d_in[0];
  const float* ln1g = (const float*)d_in[1];
  const float* ln1b = (const float*)d_in[2];
  const float* ln2g = (const float*)d_in[3];
  const float* ln2b = (const float*)d_in[4];
  const float* Wq   = (const float*)d_in[5];
  const float* bq   = (const float*)d_in[6];
  const float* Wk   = (const float*)d_in[7];
  const float* bk   = (const float*)d_in[8];
  const float* Wv   = (const float*)d_in[9];
  const float* bv   = (const float*)d_in[10];
  const float* Wo   = (const float*)d_in[11];
  const float* bo   = (const float*)d_in[12];
  const float* lq1  = (const float*)d_in[13];
  const float* lk1  = (const float*)d_in[14];
  const float* lq2  = (const float*)d_in[15];
  const float* lk2  = (const float*)d_in[16];
  const float* gnw  = (const float*)d_in[17];
  const float* gnb  = (const float*)d_in[18];
  const float* W1   = (const float*)d_in[19];
  const float* b1   = (const float*)d_in[20];
  const float* Wg   = (const float*)d_in[21];
  const float* bg   = (const float*)d_in[22];
  const float* W2   = (const float*)d_in[23];
  const float* b2   = (const float*)d_in[24];

  const int B = 2, S = 2048, D = 1024, F = 4096;
  const int M = B * S;  // 4096
  const float qscale = 0.125f;

  char* ws = (char*)d_ws;
  size_t off = 0;
  auto alloc = [&](size_t bytes) {
    char* p = ws + off;
    off += (bytes + 255) & ~(size_t)255;
    return p;
  };
  unsigned short* WqT = (unsigned short*)alloc((size_t)D * D * 2);
  unsigned short* WkT = (unsigned short*)alloc((size_t)D * D * 2);
  unsigned short* WvT = (unsigned short*)alloc((size_t)D * D * 2);
  unsigned short* WoT = (unsigned short*)alloc((size_t)D * D * 2);
  unsigned short* W1T = (unsigned short*)alloc((size_t)F * D * 2);
  unsigned short* WgT = (unsigned short*)alloc((size_t)F * F * 2);
  unsigned short* W2T = (unsigned short*)alloc((size_t)D * F * 2);
  float*          lamw= (float*)alloc(256);
  unsigned short* h_bf= (unsigned short*)alloc((size_t)M * D * 2);
  unsigned short* q_bf= (unsigned short*)alloc((size_t)M * D * 2);
  unsigned short* k_bf= (unsigned short*)alloc((size_t)M * D * 2);
  unsigned short* v_bf= (unsigned short*)alloc((size_t)M * D * 2);
  unsigned short* o_bf= (unsigned short*)alloc((size_t)M * D * 2);
  float*          x1  = (float*)alloc((size_t)M * D * 4);
  float*          x2  = (float*)alloc((size_t)M * D * 4);
  unsigned short* x2b = (unsigned short*)alloc((size_t)M * D * 2);
  unsigned short* u_bf= (unsigned short*)alloc((size_t)M * F * 2);
  unsigned short* w_bf= h_bf;   // gated act reuses h span (dead after q/k/v GEMMs)

  // Attention scratch overlays:
  //  Opart (64MB fp32) overlays x1+x2+x2b+u_bf[0:24MB) — all dead during attn.
  //  VT (8MB) in the last 8MB of the u_bf span (offset 24MB = 12M shorts).
  //  lsumP: fresh 1MB after u_bf.
  float* Opart = (float*)x1;
  float* lsumP = (float*)alloc((size_t)2 * 16 * S * 2 * 4);
  unsigned short* VT = u_bf + (size_t)12 * 1024 * 1024;

  // --- weight prep ---
  transpose_cvt<<<dim3(D / 64, D / 64), 256, 0, stream>>>(Wq, WqT, D, D, qscale);
  transpose_cvt<<<dim3(D / 64, D / 64), 256, 0, stream>>>(Wk, WkT, D, D, 1.0f);
  transpose_cvt<<<dim3(D / 64, D / 64), 256, 0, stream>>>(Wv, WvT, D, D, 1.0f);
  transpose_cvt<<<dim3(D / 64, D / 64), 256, 0, stream>>>(Wo, WoT, D, D, 1.0f);
  transpose_cvt<<<dim3(F / 64, D / 64), 256, 0, stream>>>(W1, W1T, D, F, 1.0f);
  transpose_cvt<<<dim3(F / 64, F / 64), 256, 0, stream>>>(Wg, WgT, F, F, 1.0f);
  transpose_cvt<<<dim3(D / 64, F / 64), 256, 0, stream>>>(W2, W2T, F, D, 1.0f);
  lam_kernel<<<1, 512, 0, stream>>>(lq1, lk1, lq2, lk2, lamw);

  // --- attention sublayer ---
  ln_kernel<0><<<M, 256, 0, stream>>>(x, ln1g, ln1b, h_bf, nullptr);
  gemm_bf16<0><<<dim3(D / 128, M / 128), 256, 0, stream>>>(h_bf, WqT, bq, nullptr, nullptr, q_bf, M, D, D, qscale);
  gemm_bf16<0><<<dim3(D / 128, M / 128), 256, 0, stream>>>(h_bf, WkT, bk, nullptr, nullptr, k_bf, M, D, D, 1.0f);
  gemm_bf16<0><<<dim3(D / 128, M / 128), 256, 0, stream>>>(h_bf, WvT, bv, nullptr, nullptr, v_bf, M, D, D, 1.0f);
  v_transpose<<<dim3(S / 64, 2, 16), 256, 0, stream>>>(v_bf, VT);
  attn_kernel<<<dim3(1024), 256, 0, stream>>>(q_bf, k_bf, VT, Opart, lsumP);
  attn_reduce<<<dim3(8192), 256, 0, stream>>>(Opart, lsumP, lamw, gnw, gnb, o_bf);
  gemm_bf16<1><<<dim3(D / 128, M / 128), 256, 0, stream>>>(o_bf, WoT, bo, x, nullptr, x1, M, D, D, 1.0f);

  // --- FFN sublayer ---
  ln_kernel<1><<<M, 256, 0, stream>>>(x1, ln2g, ln2b, x2b, x2);
  gemm_bf16<0><<<dim3(F / 128, M / 128), 256, 0, stream>>>(x2b, W1T, b1, nullptr, nullptr, u_bf, M, F, D, 1.0f);
  gemm_bf16<2><<<dim3(F / 128, M / 128), 256, 0, stream>>>(u_bf, WgT, bg, nullptr, u_bf, w_bf, M, F, F, 1.0f);
  gemm_bf16<1><<<dim3(D / 128, M / 128), 256, 0, stream>>>(w_bf, W2T, b2, x2, nullptr, (float*)d_out, M, D, F, 1.0f);
}